// Round 9
// baseline (492.988 us; speedup 1.0000x reference)
//
#include <hip/hip_runtime.h>
#include <hip/hip_fp16.h>

#define N_NODES 100000
#define N_EDGES 1600000
#define D 64
#define BN_EPS 1e-5f
#define NSHARD 32                // BN stat shards (r7: 8 shards -> 780-deep
                                 // same-address atomic chains = 47us stall)

// ---- CSR pipeline geometry ----
#define NBKT 256                 // dst-range buckets
#define NPB 391                  // nodes per bucket: 256*391 >= 100000
#define BKT_CAP 13056            // oversized so x16 (12.81MB) aliases bktbuf (13.37MB)
#define NBBLK 391                // bucket blocks: 391*4096 >= N_EDGES
#define SORT_T 1024

typedef _Float16 half8 __attribute__((ext_vector_type(8)));
typedef float f32x4 __attribute__((ext_vector_type(4)));

// ---------------------------------------------------------------------------
// prep_k: blockIdx-partitioned fused preprocessing (verified r2).
//   blocks [0, NBBLK)          : bucket edges, packed (src<<9)|dst_local (4B)
//   blocks [NBBLK, NBBLK+3125) : feat fp32 -> fp16 table
//   block  NBBLK+3125          : W1,W2 -> fp16 transposed tables
// ---------------------------------------------------------------------------
__global__ __launch_bounds__(256) void prep_k(
    const int* __restrict__ src, const int* __restrict__ dst,
    int* __restrict__ bkt_cnt, int* __restrict__ bktbuf,
    const float* __restrict__ feat, __half* __restrict__ feat16,
    const float* __restrict__ W1, const float* __restrict__ W2,
    _Float16* __restrict__ w1t, _Float16* __restrict__ w2t)
{
    __shared__ int h[NBKT], base[NBKT], cur[NBKT];
    const int blk = blockIdx.x;
    const int t = threadIdx.x;

    if (blk < NBBLK) {
        h[t] = 0; cur[t] = 0;
        __syncthreads();
        const int e0 = blk * 4096;
        int pk[16], b[16];
        #pragma unroll
        for (int i = 0; i < 16; ++i) {
            int e = e0 + i * 256 + t;
            if (e < N_EDGES) {
                int d = dst[e];
                b[i] = d / NPB;
                pk[i] = (src[e] << 9) | (d - b[i] * NPB);   // 17+9 bits
                atomicAdd(&h[b[i]], 1);
            } else {
                b[i] = -1;
            }
        }
        __syncthreads();
        base[t] = atomicAdd(&bkt_cnt[t], h[t]);
        __syncthreads();
        #pragma unroll
        for (int i = 0; i < 16; ++i) {
            if (b[i] >= 0) {
                int p = atomicAdd(&cur[b[i]], 1);
                bktbuf[(size_t)b[i] * BKT_CAP + base[b[i]] + p] = pk[i];
            }
        }
    } else if (blk < NBBLK + 3125) {
        size_t i = ((size_t)(blk - NBBLK) * 256 + t) * 8;
        if (i < (size_t)N_NODES * D) {
            float4 v0 = *(const float4*)(feat + i);
            float4 v1 = *(const float4*)(feat + i + 4);
            __half2 o[4];
            o[0] = __floats2half2_rn(v0.x, v0.y);
            o[1] = __floats2half2_rn(v0.z, v0.w);
            o[2] = __floats2half2_rn(v1.x, v1.y);
            o[3] = __floats2half2_rn(v1.z, v1.w);
            *(float4*)(feat16 + i) = *(float4*)o;
        }
    } else {
        const int n = t >> 2;
        const int k0 = (t & 3) * 16;
        _Float16 o1[16], o2[16];
        #pragma unroll
        for (int j = 0; j < 16; ++j) {
            o1[j] = (_Float16)W1[(k0 + j) * 64 + n];
            o2[j] = (_Float16)W2[(k0 + j) * 64 + n];
        }
        #pragma unroll
        for (int j = 0; j < 16; j += 8) {
            *(half8*)(w1t + n * 64 + k0 + j) = *(half8*)&o1[j];
            *(half8*)(w2t + n * 64 + k0 + j) = *(half8*)&o2[j];
        }
    }
}

// ---------------------------------------------------------------------------
// sortp_k: one block per bucket, packed 4B records. Shfl-based scans
// (verified r4-r8). r9: col segment staged in LDS (scatter hits LDS, global
// write is a coalesced stream) + block 0 zeroes the BN stat shards.
// ---------------------------------------------------------------------------
__device__ __forceinline__ int wscan_incl(int x, int lane)
{
    #pragma unroll
    for (int off = 1; off < 64; off <<= 1) {
        int v = __shfl_up(x, off, 64);
        if (lane >= off) x += v;
    }
    return x;
}

__global__ __launch_bounds__(SORT_T) void sortp_k(
    const int* __restrict__ bktbuf, const int* __restrict__ bkt_cnt,
    int* __restrict__ rowptr, int* __restrict__ col, float* __restrict__ stats)
{
    __shared__ int h[NPB];
    __shared__ int cur[NPB];
    __shared__ int wsum[16];
    __shared__ int colstage[BKT_CAP];      // 52.2 KB (static LDS < 64 KB)

    const int b    = blockIdx.x;
    const int t    = threadIdx.x;
    const int lane = t & 63;
    const int wv   = t >> 6;
    const int nb0  = b * NPB;
    const int nodes_in = min(NPB, N_NODES - nb0);
    const int cnt = min(bkt_cnt[b], BKT_CAP);
    const int* buf = bktbuf + (size_t)b * BKT_CAP;

    if (b == 0) {                          // zero BN stat shards (runs before mlpfin)
        for (int i = t; i < NSHARD * 128; i += SORT_T) stats[i] = 0.f;
    }

    // gbase = sum_{i<b} min(bkt_cnt[i], CAP): masked block reduce
    int ci = 0;
    if (t < NBKT && t < b) ci = min(bkt_cnt[t], BKT_CAP);
    #pragma unroll
    for (int off = 32; off >= 1; off >>= 1) ci += __shfl_xor(ci, off, 64);
    if (lane == 0) wsum[wv] = ci;
    if (t < NPB) h[t] = 0;
    __syncthreads();
    const int gbase = wsum[0] + wsum[1] + wsum[2] + wsum[3];

    // histogram over dst_local
    for (int i = t; i < cnt; i += SORT_T)
        atomicAdd(&h[buf[i] & 511], 1);
    __syncthreads();

    // exclusive scan of h[0..NPB) via wave scans + cross-wave combine
    int a = 0, x = 0;
    if (wv < 7) {                          // wave-uniform: waves 0..6 cover 448 >= NPB
        a = (t < NPB) ? h[t] : 0;
        x = wscan_incl(a, lane);
        if (lane == 63) wsum[wv] = x;
    }
    __syncthreads();
    if (wv < 7) {
        int offs = 0;
        for (int i = 0; i < wv; ++i) offs += wsum[i];
        const int excl = x - a + offs;
        if (t < NPB) {
            cur[t] = excl;
            if (t < nodes_in) rowptr[nb0 + t] = gbase + excl;
        }
    }
    if (b == NBKT - 1 && t == 0) rowptr[N_NODES] = N_EDGES;
    __syncthreads();

    // scatter into LDS stage, then coalesced stream to global
    for (int i = t; i < cnt; i += SORT_T) {
        int pk = buf[i];
        int slot = atomicAdd(&cur[pk & 511], 1);
        colstage[slot] = pk >> 9;
    }
    __syncthreads();
    for (int i = t; i < cnt; i += SORT_T)
        col[gbase + i] = colstage[i];
}

// ---------------------------------------------------------------------------
// gatherq_k: quad-per-node gather, NO cross-lane reduce (verified r2/r8).
// ---------------------------------------------------------------------------
__device__ __forceinline__ void acc16(float* a, float4 r0, float4 r1)
{
    const __half2* h0 = (const __half2*)&r0;
    const __half2* h1 = (const __half2*)&r1;
    #pragma unroll
    for (int i = 0; i < 4; ++i) {
        float2 f = __half22float2(h0[i]);
        a[2 * i]     += f.x;
        a[2 * i + 1] += f.y;
    }
    #pragma unroll
    for (int i = 0; i < 4; ++i) {
        float2 f = __half22float2(h1[i]);
        a[8 + 2 * i]     += f.x;
        a[8 + 2 * i + 1] += f.y;
    }
}

__global__ __launch_bounds__(256) void gatherq_k(
    const __half* __restrict__ feat16, const int* __restrict__ rowptr,
    const int* __restrict__ col, const float* __restrict__ epsp,
    __half* __restrict__ x16)
{
    const int t = threadIdx.x;
    const int node = blockIdx.x * 64 + (t >> 2);
    if (node >= N_NODES) return;
    const int c = (t & 3) << 4;            // half-offset of this lane's slice

    const int lo = rowptr[node];
    const int hi = rowptr[node + 1];

    float a[16];
    #pragma unroll
    for (int i = 0; i < 16; ++i) a[i] = 0.f;

    int e = lo;
    for (; e + 3 < hi; e += 4) {
        const int s0 = col[e], s1 = col[e + 1], s2 = col[e + 2], s3 = col[e + 3];
        const __half* p0 = feat16 + (size_t)s0 * 64 + c;
        const __half* p1 = feat16 + (size_t)s1 * 64 + c;
        const __half* p2 = feat16 + (size_t)s2 * 64 + c;
        const __half* p3 = feat16 + (size_t)s3 * 64 + c;
        float4 r00 = *(const float4*)(p0), r01 = *(const float4*)(p0 + 8);
        float4 r10 = *(const float4*)(p1), r11 = *(const float4*)(p1 + 8);
        float4 r20 = *(const float4*)(p2), r21 = *(const float4*)(p2 + 8);
        float4 r30 = *(const float4*)(p3), r31 = *(const float4*)(p3 + 8);
        acc16(a, r00, r01);
        acc16(a, r10, r11);
        acc16(a, r20, r21);
        acc16(a, r30, r31);
    }
    for (; e < hi; ++e) {
        const __half* p = feat16 + (size_t)col[e] * 64 + c;
        float4 r0 = *(const float4*)(p), r1 = *(const float4*)(p + 8);
        acc16(a, r0, r1);
    }

    // self term + fp16 write of this lane's 32B slice
    const float epsv = 1.0f + epsp[0];
    const size_t gb = (size_t)node * 64 + c;
    float4 s0 = *(const float4*)(feat16 + gb);
    float4 s1 = *(const float4*)(feat16 + gb + 8);
    const __half2* h0 = (const __half2*)&s0;
    const __half2* h1 = (const __half2*)&s1;
    __half2 o[8];
    #pragma unroll
    for (int i = 0; i < 4; ++i) {
        float2 f = __half22float2(h0[i]);
        o[i] = __floats2half2_rn(fmaf(epsv, f.x, a[2 * i]),
                                 fmaf(epsv, f.y, a[2 * i + 1]));
    }
    #pragma unroll
    for (int i = 0; i < 4; ++i) {
        float2 f = __half22float2(h1[i]);
        o[4 + i] = __floats2half2_rn(fmaf(epsv, f.x, a[8 + 2 * i]),
                                     fmaf(epsv, f.y, a[8 + 2 * i + 1]));
    }
    *(float4*)(x16 + gb)     = *(float4*)&o[0];
    *(float4*)(x16 + gb + 8) = *(float4*)&o[4];
}

// ---------------------------------------------------------------------------
// mlpfin_k: MFMA MLP + in-kernel grid barrier + BN finish, fused. h2 stays
// in the LDS slab (no h216 global round-trip). Grid = 1563 blocks of 256
// with __launch_bounds__(256,7): at most 7 blocks/CU needed for full
// co-residency (LDS 7x~12KB=84KB, 28 waves/CU, VGPR capped at 73), so the
// counter spin cannot deadlock; a VGPR spill would only slow it (tripwire:
// WRITE_SIZE >> 26MB). Stats coherence across XCDs: shard writes are
// device-scope atomics; phase-B reads use device-scope atomic loads.
// ---------------------------------------------------------------------------
__global__ __launch_bounds__(256, 7) void mlpfin_k(
    const __half* __restrict__ x16,
    const _Float16* __restrict__ w1t, const _Float16* __restrict__ w2t,
    const float* __restrict__ b1, const float* __restrict__ b2,
    const float* __restrict__ feat, const float* __restrict__ gamma,
    const float* __restrict__ beta, float* __restrict__ out,
    float* __restrict__ stats, int* __restrict__ counter)
{
    __shared__ __align__(16) _Float16 xts[64 * 72];
    __shared__ float bnred[4 * 128];
    __shared__ float scs[64], shs[64];

    const int t    = threadIdx.x;
    const int w    = t >> 6;
    const int lane = t & 63;
    const int m    = lane & 15;
    const int q    = lane >> 4;
    const int rbase = w * 16;
    const int nb   = blockIdx.x * 64;

    // ---- phase A: barrier-free MFMA MLP (r2/r8-verified core) ----
    const _Float16* xg = (const _Float16*)x16 + (size_t)(nb + rbase + m) * 64 + q * 8;
    half8 a0 = *(const half8*)(xg);
    half8 a1 = *(const half8*)(xg + 32);

    f32x4 acc[4];
    #pragma unroll
    for (int jt = 0; jt < 4; ++jt) {
        const float bias = b1[jt * 16 + m];
        acc[jt] = (f32x4){bias, bias, bias, bias};
        const _Float16* bw = w1t + (jt * 16 + m) * 64 + q * 8;
        half8 bf0 = *(const half8*)(bw);
        half8 bf1 = *(const half8*)(bw + 32);
        acc[jt] = __builtin_amdgcn_mfma_f32_16x16x32_f16(a0, bf0, acc[jt], 0, 0, 0);
        acc[jt] = __builtin_amdgcn_mfma_f32_16x16x32_f16(a1, bf1, acc[jt], 0, 0, 0);
    }

    #pragma unroll
    for (int jt = 0; jt < 4; ++jt)
        #pragma unroll
        for (int r = 0; r < 4; ++r)
            xts[(rbase + q * 4 + r) * 72 + jt * 16 + m] =
                (_Float16)fmaxf(acc[jt][r], 0.0f);
    asm volatile("s_waitcnt lgkmcnt(0)" ::: "memory");
    __builtin_amdgcn_sched_barrier(0);

    const _Float16* xw = &xts[(rbase + m) * 72 + q * 8];
    half8 c0 = *(const half8*)(xw);
    half8 c1 = *(const half8*)(xw + 32);

    f32x4 acc2[4];
    #pragma unroll
    for (int jt = 0; jt < 4; ++jt) {
        const float bias = b2[jt * 16 + m];
        acc2[jt] = (f32x4){bias, bias, bias, bias};
        const _Float16* bw = w2t + (jt * 16 + m) * 64 + q * 8;
        half8 bf0 = *(const half8*)(bw);
        half8 bf1 = *(const half8*)(bw + 32);
        acc2[jt] = __builtin_amdgcn_mfma_f32_16x16x32_f16(c0, bf0, acc2[jt], 0, 0, 0);
        acc2[jt] = __builtin_amdgcn_mfma_f32_16x16x32_f16(c1, bf1, acc2[jt], 0, 0, 0);
    }
    asm volatile("s_waitcnt lgkmcnt(0)" ::: "memory");  // c0/c1 reads done before overwrite
    __builtin_amdgcn_sched_barrier(0);

    float psums[4], psqs[4];
    #pragma unroll
    for (int jt = 0; jt < 4; ++jt) {
        float ps = 0.f, pq = 0.f;
        #pragma unroll
        for (int r = 0; r < 4; ++r) {
            const int row = rbase + q * 4 + r;
            const float v = acc2[jt][r];
            const float vv = (nb + row < N_NODES) ? v : 0.f;
            ps += vv;
            pq += vv * vv;
            xts[row * 72 + jt * 16 + m] = (_Float16)v;
        }
        ps += __shfl_xor(ps, 16, 64); ps += __shfl_xor(ps, 32, 64);
        pq += __shfl_xor(pq, 16, 64); pq += __shfl_xor(pq, 32, 64);
        psums[jt] = ps; psqs[jt] = pq;
    }
    if (lane < 16) {
        #pragma unroll
        for (int jt = 0; jt < 4; ++jt) {
            bnred[w * 128 + jt * 16 + lane]      = psums[jt];
            bnred[w * 128 + 64 + jt * 16 + lane] = psqs[jt];
        }
    }

    // ---- cross-wave BN fold -> one device-scope atomic per entry ----
    __syncthreads();
    if (t < 128) {
        const float v = bnred[t] + bnred[128 + t] + bnred[256 + t] + bnred[384 + t];
        unsafeAtomicAdd(stats + (size_t)(blockIdx.x & (NSHARD - 1)) * 128 + t, v);
    }
    __threadfence();          // make this block's stat atomics device-visible
    __syncthreads();

    // ---- grid barrier: counter spin (all blocks co-resident by bounds) ----
    if (t == 0) {
        __hip_atomic_fetch_add(counter, 1, __ATOMIC_ACQ_REL, __HIP_MEMORY_SCOPE_AGENT);
        while (__hip_atomic_load(counter, __ATOMIC_ACQUIRE, __HIP_MEMORY_SCOPE_AGENT)
               < (int)gridDim.x) {}
    }
    __syncthreads();

    // ---- phase B: fold shards (coherent atomic loads), BN+relu+residual ----
    if (t < 128) {
        float s = 0.f;
        #pragma unroll
        for (int c = 0; c < NSHARD; ++c)
            s += __hip_atomic_load(stats + c * 128 + t, __ATOMIC_RELAXED,
                                   __HIP_MEMORY_SCOPE_AGENT);
        bnred[t] = s;
    }
    __syncthreads();
    if (t < 64) {
        const float invN = 1.0f / (float)N_NODES;
        const float mean = bnred[t] * invN;
        const float var  = bnred[64 + t] * invN - mean * mean;
        const float scale = gamma[t] * rsqrtf(var + BN_EPS);
        scs[t] = scale;
        shs[t] = beta[t] - mean * scale;
    }
    __syncthreads();
    {
        const int rr = lane >> 2;
        const int cc = (lane & 3) * 16;
        const int gn = nb + rbase + rr;
        if (gn < N_NODES) {
            float4 r0 = *(const float4*)&xts[(rbase + rr) * 72 + cc];
            float4 r1 = *(const float4*)&xts[(rbase + rr) * 72 + cc + 8];
            const __half2* hh0 = (const __half2*)&r0;
            const __half2* hh1 = (const __half2*)&r1;
            const float* frow = feat + (size_t)gn * 64 + cc;
            float* orow = out + (size_t)gn * 64 + cc;
            #pragma unroll
            for (int i = 0; i < 2; ++i) {
                float4 f0 = *(const float4*)(frow + i * 8);
                float4 f1 = *(const float4*)(frow + i * 8 + 4);
                float2 ha = __half22float2(hh0[i * 2 + (i == 0 ? 0 : 0)]);
                // unpack 8 halves of this 8-col group
                const __half2* hp = (i == 0) ? hh0 : hh1;
                float2 v0 = __half22float2(hp[0]);
                float2 v1 = __half22float2(hp[1]);
                float2 v2 = __half22float2(hp[2]);
                float2 v3 = __half22float2(hp[3]);
                const int j = cc + i * 8;
                float4 o0, o1;
                o0.x = fmaxf(fmaf(v0.x, scs[j + 0], shs[j + 0]), 0.f) + f0.x;
                o0.y = fmaxf(fmaf(v0.y, scs[j + 1], shs[j + 1]), 0.f) + f0.y;
                o0.z = fmaxf(fmaf(v1.x, scs[j + 2], shs[j + 2]), 0.f) + f0.z;
                o0.w = fmaxf(fmaf(v1.y, scs[j + 3], shs[j + 3]), 0.f) + f0.w;
                o1.x = fmaxf(fmaf(v2.x, scs[j + 4], shs[j + 4]), 0.f) + f1.x;
                o1.y = fmaxf(fmaf(v2.y, scs[j + 5], shs[j + 5]), 0.f) + f1.y;
                o1.z = fmaxf(fmaf(v3.x, scs[j + 6], shs[j + 6]), 0.f) + f1.z;
                o1.w = fmaxf(fmaf(v3.y, scs[j + 7], shs[j + 7]), 0.f) + f1.w;
                *(float4*)(orow + i * 8)     = o0;
                *(float4*)(orow + i * 8 + 4) = o1;
                (void)ha;
            }
        }
    }
}

// ===========================================================================
// fp32 fallback path (old CSR pipeline, int2 records), if workspace small.
// ===========================================================================
#define OCAP 7680

__global__ void bnstats_k(const float* __restrict__ stats,
                          const float* __restrict__ gamma,
                          const float* __restrict__ beta,
                          float* __restrict__ sf)
{
    int j = threadIdx.x;
    float s = 0.f, q = 0.f;
    for (int c = 0; c < NSHARD; ++c) {
        s += stats[c * 128 + j];
        q += stats[c * 128 + 64 + j];
    }
    const float invN = 1.0f / (float)N_NODES;
    float mean  = s * invN;
    float var   = q * invN - mean * mean;
    float scale = gamma[j] * rsqrtf(var + BN_EPS);
    sf[j]      = scale;
    sf[64 + j] = beta[j] - mean * scale;
}

__global__ __launch_bounds__(256) void bucket2_k(
    const int* __restrict__ src, const int* __restrict__ dst,
    int* __restrict__ bkt_cnt, int2* __restrict__ bktbuf)
{
    __shared__ int h[NBKT], base[NBKT], cur[NBKT];
    const int t = threadIdx.x;
    h[t] = 0; cur[t] = 0;
    __syncthreads();
    const int e0 = blockIdx.x * 4096;
    int s[16], d[16], b[16];
    #pragma unroll
    for (int i = 0; i < 16; ++i) {
        int e = e0 + i * 256 + t;
        if (e < N_EDGES) {
            s[i] = src[e];
            d[i] = dst[e];
            b[i] = d[i] / NPB;
            atomicAdd(&h[b[i]], 1);
        } else {
            b[i] = -1;
        }
    }
    __syncthreads();
    base[t] = atomicAdd(&bkt_cnt[t], h[t]);
    __syncthreads();
    #pragma unroll
    for (int i = 0; i < 16; ++i) {
        if (b[i] >= 0) {
            int p = atomicAdd(&cur[b[i]], 1);
            bktbuf[(size_t)b[i] * OCAP + base[b[i]] + p] = make_int2(s[i], d[i]);
        }
    }
}

__global__ __launch_bounds__(SORT_T) void sort2_k(
    const int2* __restrict__ bktbuf, const int* __restrict__ bkt_cnt,
    int* __restrict__ rowptr, int* __restrict__ col)
{
    __shared__ int h[NPB];
    __shared__ int cur[NPB];
    __shared__ int part[SORT_T];
    __shared__ int bsc[NBKT];

    const int b = blockIdx.x;
    const int t = threadIdx.x;
    const int nb0 = b * NPB;
    const int nodes_in = min(NPB, N_NODES - nb0);
    const int cnt = bkt_cnt[b];
    const int2* buf = bktbuf + (size_t)b * OCAP;

    if (t < NBKT) bsc[t] = bkt_cnt[t];
    __syncthreads();
    for (int off = 1; off < NBKT; off <<= 1) {
        int x = 0;
        if (t < NBKT) {
            x = bsc[t];
            if (t >= off) x += bsc[t - off];
        }
        __syncthreads();
        if (t < NBKT) bsc[t] = x;
        __syncthreads();
    }
    const int gbase = bsc[b] - cnt;

    if (t < NPB) h[t] = 0;
    __syncthreads();

    for (int i = t; i < cnt; i += SORT_T)
        atomicAdd(&h[buf[i].y - nb0], 1);
    __syncthreads();

    int a = (t < NPB) ? h[t] : 0;
    part[t] = a;
    __syncthreads();
    for (int off = 1; off < SORT_T; off <<= 1) {
        int x = part[t];
        int u = (t >= off) ? part[t - off] : 0;
        __syncthreads();
        part[t] = x + u;
        __syncthreads();
    }
    int excl = part[t] - a;
    if (t < NPB) {
        cur[t] = excl;
        if (t < nodes_in) rowptr[nb0 + t] = gbase + excl;
    }
    if (b == NBKT - 1 && t == 0) rowptr[N_NODES] = N_EDGES;
    __syncthreads();

    for (int i = t; i < cnt; i += SORT_T) {
        int2 r = buf[i];
        int slot = atomicAdd(&cur[r.y - nb0], 1);
        col[gbase + slot] = r.x;
    }
}

__global__ __launch_bounds__(256) void gather32_k(
    const float* __restrict__ feat, const int* __restrict__ rowptr,
    const int* __restrict__ col, const float* __restrict__ epsp,
    float* __restrict__ x)
{
    int node = blockIdx.x * 4 + (threadIdx.x >> 6);
    int lane = threadIdx.x & 63;
    if (node >= N_NODES) return;
    int g = lane >> 4;
    int c = (lane & 15) << 2;
    int lo = rowptr[node];
    int hi = rowptr[node + 1];
    float ax = 0.f, ay = 0.f, az = 0.f, aw = 0.f;
    int e = lo + g;
    for (; e + 4 < hi; e += 8) {
        int s0 = col[e];
        int s1 = col[e + 4];
        float4 v0 = *(const float4*)(feat + (size_t)s0 * D + c);
        float4 v1 = *(const float4*)(feat + (size_t)s1 * D + c);
        ax += v0.x; ay += v0.y; az += v0.z; aw += v0.w;
        ax += v1.x; ay += v1.y; az += v1.z; aw += v1.w;
    }
    if (e < hi) {
        float4 v = *(const float4*)(feat + (size_t)col[e] * D + c);
        ax += v.x; ay += v.y; az += v.z; aw += v.w;
    }
    #pragma unroll
    for (int off = 16; off <= 32; off <<= 1) {
        ax += __shfl_xor(ax, off, 64);
        ay += __shfl_xor(ay, off, 64);
        az += __shfl_xor(az, off, 64);
        aw += __shfl_xor(aw, off, 64);
    }
    if (g == 0) {
        float4 f = *(const float4*)(feat + (size_t)node * D + c);
        const float epsv = 1.0f + epsp[0];
        float4 r;
        r.x = fmaf(epsv, f.x, ax);
        r.y = fmaf(epsv, f.y, ay);
        r.z = fmaf(epsv, f.z, az);
        r.w = fmaf(epsv, f.w, aw);
        *(float4*)(x + (size_t)node * D + c) = r;
    }
}

__global__ __launch_bounds__(256) void mlp32_k(
    const float* __restrict__ x,
    const float* __restrict__ W1, const float* __restrict__ b1,
    const float* __restrict__ W2, const float* __restrict__ b2,
    float* __restrict__ h2out, float* __restrict__ stats)
{
    __shared__ float W1s[64 * 68];
    __shared__ float W2s[64 * 68];
    __shared__ float xs[64 * 65];
    __shared__ float b1s[64], b2s[64];

    const int t  = threadIdx.x;
    const int nb = blockIdx.x * 64;

    #pragma unroll
    for (int i = 0; i < 4; ++i) {
        int l  = t + i * 256;
        int k  = l >> 4;
        int j4 = (l & 15) << 2;
        *(float4*)(&W1s[k * 68 + j4]) = *(const float4*)(W1 + k * 64 + j4);
        *(float4*)(&W2s[k * 68 + j4]) = *(const float4*)(W2 + k * 64 + j4);
    }
    if (t < 64)       b1s[t]      = b1[t];
    else if (t < 128) b2s[t - 64] = b2[t - 64];

    #pragma unroll
    for (int i = 0; i < 2; ++i) {
        int n  = (t >> 3) + i * 32;
        int k8 = (t & 7) << 3;
        int gn = nb + n;
        float4 a = make_float4(0.f, 0.f, 0.f, 0.f), b = a;
        if (gn < N_NODES) {
            a = *(const float4*)(x + (size_t)gn * D + k8);
            b = *(const float4*)(x + (size_t)gn * D + k8 + 4);
        }
        *(float4*)&xs[n * 65 + k8]     = a;
        *(float4*)&xs[n * 65 + k8 + 4] = b;
    }
    __syncthreads();

    const int n0 = (t & 15) << 2;
    const int j0 = (t >> 4) << 2;
    const float* xr0 = &xs[(n0 + 0) * 65];
    const float* xr1 = &xs[(n0 + 1) * 65];
    const float* xr2 = &xs[(n0 + 2) * 65];
    const float* xr3 = &xs[(n0 + 3) * 65];

    float acc[4][4];
    #pragma unroll
    for (int a = 0; a < 4; ++a)
        #pragma unroll
        for (int b = 0; b < 4; ++b)
            acc[a][b] = b1s[j0 + b];

    #pragma unroll 8
    for (int k = 0; k < 64; ++k) {
        const float4 w = *(const float4*)(&W1s[k * 68 + j0]);
        const float x0 = xr0[k], x1 = xr1[k], x2 = xr2[k], x3 = xr3[k];
        acc[0][0] = fmaf(x0, w.x, acc[0][0]); acc[0][1] = fmaf(x0, w.y, acc[0][1]);
        acc[0][2] = fmaf(x0, w.z, acc[0][2]); acc[0][3] = fmaf(x0, w.w, acc[0][3]);
        acc[1][0] = fmaf(x1, w.x, acc[1][0]); acc[1][1] = fmaf(x1, w.y, acc[1][1]);
        acc[1][2] = fmaf(x1, w.z, acc[1][2]); acc[1][3] = fmaf(x1, w.w, acc[1][3]);
        acc[2][0] = fmaf(x2, w.x, acc[2][0]); acc[2][1] = fmaf(x2, w.y, acc[2][1]);
        acc[2][2] = fmaf(x2, w.z, acc[2][2]); acc[2][3] = fmaf(x2, w.w, acc[2][3]);
        acc[3][0] = fmaf(x3, w.x, acc[3][0]); acc[3][1] = fmaf(x3, w.y, acc[3][1]);
        acc[3][2] = fmaf(x3, w.z, acc[3][2]); acc[3][3] = fmaf(x3, w.w, acc[3][3]);
    }

    __syncthreads();
    #pragma unroll
    for (int a = 0; a < 4; ++a)
        #pragma unroll
        for (int b = 0; b < 4; ++b)
            xs[(n0 + a) * 65 + j0 + b] = fmaxf(acc[a][b], 0.0f);
    __syncthreads();

    float acc2[4][4];
    #pragma unroll
    for (int a = 0; a < 4; ++a)
        #pragma unroll
        for (int b = 0; b < 4; ++b)
            acc2[a][b] = b2s[j0 + b];

    #pragma unroll 8
    for (int k = 0; k < 64; ++k) {
        const float4 w = *(const float4*)(&W2s[k * 68 + j0]);
        const float x0 = xr0[k], x1 = xr1[k], x2 = xr2[k], x3 = xr3[k];
        acc2[0][0] = fmaf(x0, w.x, acc2[0][0]); acc2[0][1] = fmaf(x0, w.y, acc2[0][1]);
        acc2[0][2] = fmaf(x0, w.z, acc2[0][2]); acc2[0][3] = fmaf(x0, w.w, acc2[0][3]);
        acc2[1][0] = fmaf(x1, w.x, acc2[1][0]); acc2[1][1] = fmaf(x1, w.y, acc2[1][1]);
        acc2[1][2] = fmaf(x1, w.z, acc2[1][2]); acc2[1][3] = fmaf(x1, w.w, acc2[1][3]);
        acc2[2][0] = fmaf(x2, w.x, acc2[2][0]); acc2[2][1] = fmaf(x2, w.y, acc2[2][1]);
        acc2[2][2] = fmaf(x2, w.z, acc2[2][2]); acc2[2][3] = fmaf(x2, w.w, acc2[2][3]);
        acc2[3][0] = fmaf(x3, w.x, acc2[3][0]); acc2[3][1] = fmaf(x3, w.y, acc2[3][1]);
        acc2[3][2] = fmaf(x3, w.z, acc2[3][2]); acc2[3][3] = fmaf(x3, w.w, acc2[3][3]);
    }

    float psum[4] = {0.f, 0.f, 0.f, 0.f};
    float psq[4]  = {0.f, 0.f, 0.f, 0.f};
    #pragma unroll
    for (int a = 0; a < 4; ++a) {
        int gn = nb + n0 + a;
        if (gn < N_NODES) {
            float4 hh;
            hh.x = acc2[a][0]; hh.y = acc2[a][1]; hh.z = acc2[a][2]; hh.w = acc2[a][3];
            *(float4*)(h2out + (size_t)gn * 64 + j0) = hh;
            psum[0] += hh.x; psq[0] += hh.x * hh.x;
            psum[1] += hh.y; psq[1] += hh.y * hh.y;
            psum[2] += hh.z; psq[2] += hh.z * hh.z;
            psum[3] += hh.w; psq[3] += hh.w * hh.w;
        }
    }
    #pragma unroll
    for (int off = 8; off >= 1; off >>= 1)
        #pragma unroll
        for (int b = 0; b < 4; ++b) {
            psum[b] += __shfl_down(psum[b], off, 16);
            psq[b]  += __shfl_down(psq[b],  off, 16);
        }
    if ((t & 15) == 0) {
        float* sp = stats + (size_t)(blockIdx.x & (NSHARD - 1)) * 128;
        #pragma unroll
        for (int b = 0; b < 4; ++b) {
            unsafeAtomicAdd(sp + j0 + b,      psum[b]);
            unsafeAtomicAdd(sp + 64 + j0 + b, psq[b]);
        }
    }
}

__global__ __launch_bounds__(256) void finish_k(
    const float* __restrict__ feat, const float* __restrict__ sf,
    float* __restrict__ out)
{
    __shared__ float scs[64], shs[64];
    if (threadIdx.x < 64) {
        scs[threadIdx.x] = sf[threadIdx.x];
        shs[threadIdx.x] = sf[64 + threadIdx.x];
    }
    __syncthreads();
    size_t i = (size_t)blockIdx.x * 256 + threadIdx.x;
    if (i < (size_t)N_NODES * D / 4) {
        int j = (int)((i * 4) & 63);
        float4 h = *(float4*)(out + i * 4);
        float4 f = *(const float4*)(feat + i * 4);
        h.x = fmaxf(fmaf(h.x, scs[j + 0], shs[j + 0]), 0.f) + f.x;
        h.y = fmaxf(fmaf(h.y, scs[j + 1], shs[j + 1]), 0.f) + f.y;
        h.z = fmaxf(fmaf(h.z, scs[j + 2], shs[j + 2]), 0.f) + f.z;
        h.w = fmaxf(fmaf(h.w, scs[j + 3], shs[j + 3]), 0.f) + f.w;
        *(float4*)(out + i * 4) = h;
    }
}

extern "C" void kernel_launch(void* const* d_in, const int* in_sizes, int n_in,
                              void* d_out, int out_size, void* d_ws, size_t ws_size,
                              hipStream_t stream)
{
    const float* feat  = (const float*)d_in[0];
    const int*   src   = (const int*)d_in[1];
    const int*   dst   = (const int*)d_in[2];
    const float* eps   = (const float*)d_in[3];
    const float* W1    = (const float*)d_in[4];
    const float* b1    = (const float*)d_in[5];
    const float* W2    = (const float*)d_in[6];
    const float* b2    = (const float*)d_in[7];
    const float* gamma = (const float*)d_in[8];
    const float* beta  = (const float*)d_in[9];
    float* out = (float*)d_out;

    const size_t BKTSZ  = (size_t)NBKT * BKT_CAP * sizeof(int);    // 13.37 MB
    const size_t F16SZ  = (size_t)N_NODES * D * sizeof(__half);    // 12.8 MB
    const size_t COLSZ  = (size_t)N_EDGES * sizeof(int);           // 6.4 MB
    const size_t RPSZ   = ((size_t)(N_NODES + 1) * sizeof(int) + 15) & ~(size_t)15;
    const size_t STATSZ = (size_t)NSHARD * 128 * sizeof(float);    // 16 KB
    const size_t CNTSZ  = (size_t)NBKT * sizeof(int);              // 1 KB
    const size_t TAIL   = STATSZ + CNTSZ + 128 * 4 + 2 * 4096 * sizeof(_Float16) + 512;
    const size_t need   = BKTSZ + F16SZ + COLSZ + RPSZ + TAIL;     // ~33.2 MB

    if (ws_size >= need) {
        // fp16 path (r2-verified layout). x16 aliases bktbuf (dead after
        // sortp_k; BKT_CAP oversized to cover x16 + mlpfin 64-row tail
        // overread). h216 eliminated entirely (h2 lives in mlpfin's LDS).
        char* p = (char*)d_ws;
        int*    bktbuf  = (int*)p;
        __half* x16     = (__half*)p;
        __half* feat16  = (__half*)(p + BKTSZ);
        int*    col     = (int*)(p + BKTSZ + F16SZ);
        int*    rowptr  = (int*)(p + BKTSZ + F16SZ + COLSZ);
        float*  stats   = (float*)(p + BKTSZ + F16SZ + COLSZ + RPSZ);
        int*    bkt_cnt = (int*)(stats + NSHARD * 128);
        int*    counter = bkt_cnt + NBKT;
        _Float16* w1t   = (_Float16*)(counter + 16);
        _Float16* w2t   = w1t + 4096;

        // zero bkt_cnt + counter (stats zeroed by sortp block 0)
        hipMemsetAsync(bkt_cnt, 0, CNTSZ + 64, stream);
        prep_k<<<NBBLK + 3125 + 1, 256, 0, stream>>>(src, dst, bkt_cnt, bktbuf,
                                                     feat, feat16, W1, W2, w1t, w2t);
        sortp_k<<<NBKT, SORT_T, 0, stream>>>(bktbuf, bkt_cnt, rowptr, col, stats);
        gatherq_k<<<(N_NODES + 63) / 64, 256, 0, stream>>>(feat16, rowptr, col, eps, x16);
        mlpfin_k<<<(N_NODES + 63) / 64, 256, 0, stream>>>(
            x16, w1t, w2t, b1, b2, feat, gamma, beta, out, stats, counter);
    } else {
        // fp32 fallback (old CSR pipeline, int2 records). x32 aliases bktbuf.
        const size_t X32SZ = (size_t)N_NODES * D * sizeof(float);
        char* p = (char*)d_ws;
        float* x32    = (float*)p;
        int2*  bktbuf = (int2*)p;
        int*   col    = (int*)(p + X32SZ);
        int*   rowptr = col + N_EDGES;
        float* stats  = (float*)(rowptr + N_NODES + 1);
        int*   bkt_cnt = (int*)(stats + NSHARD * 128);
        float* sf     = (float*)(bkt_cnt + NBKT);

        hipMemsetAsync(stats, 0, STATSZ + NBKT * 4, stream);
        bucket2_k<<<(N_EDGES + 4095) / 4096, 256, 0, stream>>>(src, dst, bkt_cnt, bktbuf);
        sort2_k<<<NBKT, SORT_T, 0, stream>>>(bktbuf, bkt_cnt, rowptr, col);
        gather32_k<<<(N_NODES + 3) / 4, 256, 0, stream>>>(feat, rowptr, col, eps, x32);
        mlp32_k<<<(N_NODES + 63) / 64, 256, 0, stream>>>(x32, W1, b1, W2, b2, out, stats);
        bnstats_k<<<1, 64, 0, stream>>>(stats, gamma, beta, sf);
        finish_k<<<(N_NODES * D / 4 + 255) / 256, 256, 0, stream>>>(feat, sf, out);
    }
}

// Round 10
// 192.005 us; speedup vs baseline: 2.5676x; 2.5676x over previous
//
#include <hip/hip_runtime.h>
#include <hip/hip_fp16.h>

#define N_NODES 100000
#define N_EDGES 1600000
#define D 64
#define BN_EPS 1e-5f
#define NSHARD 32                // BN stat shards (r7: 8 shards -> 780-deep
                                 // same-address atomic chains = 47us stall)

// ---- CSR pipeline geometry ----
#define NBKT 256                 // dst-range buckets
#define NPB 391                  // nodes per bucket: 256*391 >= 100000
#define BKT_CAP 13056            // oversized so x16 (12.81MB) aliases bktbuf (13.37MB)
#define NBBLK 391                // bucket blocks: 391*4096 >= N_EDGES
#define SORT_T 1024

typedef _Float16 half8 __attribute__((ext_vector_type(8)));
typedef float f32x4 __attribute__((ext_vector_type(4)));

// ---------------------------------------------------------------------------
// prep_k: blockIdx-partitioned fused preprocessing (verified r2-r9).
//   blocks [0, NBBLK)          : bucket edges, packed (src<<9)|dst_local (4B)
//   blocks [NBBLK, NBBLK+3125) : feat fp32 -> fp16 table
//   block  NBBLK+3125          : W1,W2 -> fp16 transposed tables
// ---------------------------------------------------------------------------
__global__ __launch_bounds__(256) void prep_k(
    const int* __restrict__ src, const int* __restrict__ dst,
    int* __restrict__ bkt_cnt, int* __restrict__ bktbuf,
    const float* __restrict__ feat, __half* __restrict__ feat16,
    const float* __restrict__ W1, const float* __restrict__ W2,
    _Float16* __restrict__ w1t, _Float16* __restrict__ w2t)
{
    __shared__ int h[NBKT], base[NBKT], cur[NBKT];
    const int blk = blockIdx.x;
    const int t = threadIdx.x;

    if (blk < NBBLK) {
        h[t] = 0; cur[t] = 0;
        __syncthreads();
        const int e0 = blk * 4096;
        int pk[16], b[16];
        #pragma unroll
        for (int i = 0; i < 16; ++i) {
            int e = e0 + i * 256 + t;
            if (e < N_EDGES) {
                int d = dst[e];
                b[i] = d / NPB;
                pk[i] = (src[e] << 9) | (d - b[i] * NPB);   // 17+9 bits
                atomicAdd(&h[b[i]], 1);
            } else {
                b[i] = -1;
            }
        }
        __syncthreads();
        base[t] = atomicAdd(&bkt_cnt[t], h[t]);
        __syncthreads();
        #pragma unroll
        for (int i = 0; i < 16; ++i) {
            if (b[i] >= 0) {
                int p = atomicAdd(&cur[b[i]], 1);
                bktbuf[(size_t)b[i] * BKT_CAP + base[b[i]] + p] = pk[i];
            }
        }
    } else if (blk < NBBLK + 3125) {
        size_t i = ((size_t)(blk - NBBLK) * 256 + t) * 8;
        if (i < (size_t)N_NODES * D) {
            float4 v0 = *(const float4*)(feat + i);
            float4 v1 = *(const float4*)(feat + i + 4);
            __half2 o[4];
            o[0] = __floats2half2_rn(v0.x, v0.y);
            o[1] = __floats2half2_rn(v0.z, v0.w);
            o[2] = __floats2half2_rn(v1.x, v1.y);
            o[3] = __floats2half2_rn(v1.z, v1.w);
            *(float4*)(feat16 + i) = *(float4*)o;
        }
    } else {
        const int n = t >> 2;
        const int k0 = (t & 3) * 16;
        _Float16 o1[16], o2[16];
        #pragma unroll
        for (int j = 0; j < 16; ++j) {
            o1[j] = (_Float16)W1[(k0 + j) * 64 + n];
            o2[j] = (_Float16)W2[(k0 + j) * 64 + n];
        }
        #pragma unroll
        for (int j = 0; j < 16; j += 8) {
            *(half8*)(w1t + n * 64 + k0 + j) = *(half8*)&o1[j];
            *(half8*)(w2t + n * 64 + k0 + j) = *(half8*)&o2[j];
        }
    }
}

// ---------------------------------------------------------------------------
// sortp_k: one block per bucket, packed 4B records. Shfl-based scans
// (verified r4-r9). Col segment staged in LDS (scatter hits LDS, global
// write is a coalesced stream — verified r9). Block 0 zeroes the BN stat
// shards, replacing that part of the memset.
// ---------------------------------------------------------------------------
__device__ __forceinline__ int wscan_incl(int x, int lane)
{
    #pragma unroll
    for (int off = 1; off < 64; off <<= 1) {
        int v = __shfl_up(x, off, 64);
        if (lane >= off) x += v;
    }
    return x;
}

__global__ __launch_bounds__(SORT_T) void sortp_k(
    const int* __restrict__ bktbuf, const int* __restrict__ bkt_cnt,
    int* __restrict__ rowptr, int* __restrict__ col, float* __restrict__ stats)
{
    __shared__ int h[NPB];
    __shared__ int cur[NPB];
    __shared__ int wsum[16];
    __shared__ int colstage[BKT_CAP];      // 52.2 KB (static LDS < 64 KB)

    const int b    = blockIdx.x;
    const int t    = threadIdx.x;
    const int lane = t & 63;
    const int wv   = t >> 6;
    const int nb0  = b * NPB;
    const int nodes_in = min(NPB, N_NODES - nb0);
    const int cnt = min(bkt_cnt[b], BKT_CAP);
    const int* buf = bktbuf + (size_t)b * BKT_CAP;

    if (b == 0) {                          // zero BN stat shards (runs before mfma_mlp2)
        for (int i = t; i < NSHARD * 128; i += SORT_T) stats[i] = 0.f;
    }

    // gbase = sum_{i<b} min(bkt_cnt[i], CAP): masked block reduce
    int ci = 0;
    if (t < NBKT && t < b) ci = min(bkt_cnt[t], BKT_CAP);
    #pragma unroll
    for (int off = 32; off >= 1; off >>= 1) ci += __shfl_xor(ci, off, 64);
    if (lane == 0) wsum[wv] = ci;
    if (t < NPB) h[t] = 0;
    __syncthreads();
    const int gbase = wsum[0] + wsum[1] + wsum[2] + wsum[3];

    // histogram over dst_local
    for (int i = t; i < cnt; i += SORT_T)
        atomicAdd(&h[buf[i] & 511], 1);
    __syncthreads();

    // exclusive scan of h[0..NPB) via wave scans + cross-wave combine
    int a = 0, x = 0;
    if (wv < 7) {                          // wave-uniform: waves 0..6 cover 448 >= NPB
        a = (t < NPB) ? h[t] : 0;
        x = wscan_incl(a, lane);
        if (lane == 63) wsum[wv] = x;
    }
    __syncthreads();
    if (wv < 7) {
        int offs = 0;
        for (int i = 0; i < wv; ++i) offs += wsum[i];
        const int excl = x - a + offs;
        if (t < NPB) {
            cur[t] = excl;
            if (t < nodes_in) rowptr[nb0 + t] = gbase + excl;
        }
    }
    if (b == NBKT - 1 && t == 0) rowptr[N_NODES] = N_EDGES;
    __syncthreads();

    // scatter into LDS stage, then coalesced stream to global
    for (int i = t; i < cnt; i += SORT_T) {
        int pk = buf[i];
        int slot = atomicAdd(&cur[pk & 511], 1);
        colstage[slot] = pk >> 9;
    }
    __syncthreads();
    for (int i = t; i < cnt; i += SORT_T)
        col[gbase + i] = colstage[i];
}

// ---------------------------------------------------------------------------
// gatherq_k: quad-per-node gather, NO cross-lane reduce (verified r2/r8).
// ---------------------------------------------------------------------------
__device__ __forceinline__ void acc16(float* a, float4 r0, float4 r1)
{
    const __half2* h0 = (const __half2*)&r0;
    const __half2* h1 = (const __half2*)&r1;
    #pragma unroll
    for (int i = 0; i < 4; ++i) {
        float2 f = __half22float2(h0[i]);
        a[2 * i]     += f.x;
        a[2 * i + 1] += f.y;
    }
    #pragma unroll
    for (int i = 0; i < 4; ++i) {
        float2 f = __half22float2(h1[i]);
        a[8 + 2 * i]     += f.x;
        a[8 + 2 * i + 1] += f.y;
    }
}

__global__ __launch_bounds__(256) void gatherq_k(
    const __half* __restrict__ feat16, const int* __restrict__ rowptr,
    const int* __restrict__ col, const float* __restrict__ epsp,
    __half* __restrict__ x16)
{
    const int t = threadIdx.x;
    const int node = blockIdx.x * 64 + (t >> 2);
    if (node >= N_NODES) return;
    const int c = (t & 3) << 4;            // half-offset of this lane's slice

    const int lo = rowptr[node];
    const int hi = rowptr[node + 1];

    float a[16];
    #pragma unroll
    for (int i = 0; i < 16; ++i) a[i] = 0.f;

    int e = lo;
    for (; e + 3 < hi; e += 4) {
        const int s0 = col[e], s1 = col[e + 1], s2 = col[e + 2], s3 = col[e + 3];
        const __half* p0 = feat16 + (size_t)s0 * 64 + c;
        const __half* p1 = feat16 + (size_t)s1 * 64 + c;
        const __half* p2 = feat16 + (size_t)s2 * 64 + c;
        const __half* p3 = feat16 + (size_t)s3 * 64 + c;
        float4 r00 = *(const float4*)(p0), r01 = *(const float4*)(p0 + 8);
        float4 r10 = *(const float4*)(p1), r11 = *(const float4*)(p1 + 8);
        float4 r20 = *(const float4*)(p2), r21 = *(const float4*)(p2 + 8);
        float4 r30 = *(const float4*)(p3), r31 = *(const float4*)(p3 + 8);
        acc16(a, r00, r01);
        acc16(a, r10, r11);
        acc16(a, r20, r21);
        acc16(a, r30, r31);
    }
    for (; e < hi; ++e) {
        const __half* p = feat16 + (size_t)col[e] * 64 + c;
        float4 r0 = *(const float4*)(p), r1 = *(const float4*)(p + 8);
        acc16(a, r0, r1);
    }

    // self term + fp16 write of this lane's 32B slice
    const float epsv = 1.0f + epsp[0];
    const size_t gb = (size_t)node * 64 + c;
    float4 s0 = *(const float4*)(feat16 + gb);
    float4 s1 = *(const float4*)(feat16 + gb + 8);
    const __half2* h0 = (const __half2*)&s0;
    const __half2* h1 = (const __half2*)&s1;
    __half2 o[8];
    #pragma unroll
    for (int i = 0; i < 4; ++i) {
        float2 f = __half22float2(h0[i]);
        o[i] = __floats2half2_rn(fmaf(epsv, f.x, a[2 * i]),
                                 fmaf(epsv, f.y, a[2 * i + 1]));
    }
    #pragma unroll
    for (int i = 0; i < 4; ++i) {
        float2 f = __half22float2(h1[i]);
        o[4 + i] = __floats2half2_rn(fmaf(epsv, f.x, a[8 + 2 * i]),
                                     fmaf(epsv, f.y, a[8 + 2 * i + 1]));
    }
    *(float4*)(x16 + gb)     = *(float4*)&o[0];
    *(float4*)(x16 + gb + 8) = *(float4*)&o[4];
}

// ---------------------------------------------------------------------------
// mfma_mlp2_k: barrier-free MFMA MLP (verified r8 at <=42us). BN partials
// fold across the block's 4 waves in LDS (one __syncthreads at the end),
// then ONE atomic per stat entry per block -> chain depth ~49.
// ---------------------------------------------------------------------------
__global__ __launch_bounds__(256) void mfma_mlp2_k(
    const __half* __restrict__ x16,
    const _Float16* __restrict__ w1t, const _Float16* __restrict__ w2t,
    const float* __restrict__ b1, const float* __restrict__ b2,
    __half* __restrict__ h216, float* __restrict__ stats)
{
    __shared__ __align__(16) _Float16 xts[64 * 72];
    __shared__ float bnred[4 * 128];

    const int t    = threadIdx.x;
    const int w    = t >> 6;
    const int lane = t & 63;
    const int m    = lane & 15;
    const int q    = lane >> 4;
    const int rbase = w * 16;
    const int nb   = blockIdx.x * 64;

    const _Float16* xg = (const _Float16*)x16 + (size_t)(nb + rbase + m) * 64 + q * 8;
    half8 a0 = *(const half8*)(xg);
    half8 a1 = *(const half8*)(xg + 32);

    f32x4 acc[4];
    #pragma unroll
    for (int jt = 0; jt < 4; ++jt) {
        const float bias = b1[jt * 16 + m];
        acc[jt] = (f32x4){bias, bias, bias, bias};
        const _Float16* bw = w1t + (jt * 16 + m) * 64 + q * 8;
        half8 bf0 = *(const half8*)(bw);
        half8 bf1 = *(const half8*)(bw + 32);
        acc[jt] = __builtin_amdgcn_mfma_f32_16x16x32_f16(a0, bf0, acc[jt], 0, 0, 0);
        acc[jt] = __builtin_amdgcn_mfma_f32_16x16x32_f16(a1, bf1, acc[jt], 0, 0, 0);
    }

    #pragma unroll
    for (int jt = 0; jt < 4; ++jt)
        #pragma unroll
        for (int r = 0; r < 4; ++r)
            xts[(rbase + q * 4 + r) * 72 + jt * 16 + m] =
                (_Float16)fmaxf(acc[jt][r], 0.0f);
    asm volatile("s_waitcnt lgkmcnt(0)" ::: "memory");
    __builtin_amdgcn_sched_barrier(0);

    const _Float16* xw = &xts[(rbase + m) * 72 + q * 8];
    half8 c0 = *(const half8*)(xw);
    half8 c1 = *(const half8*)(xw + 32);

    f32x4 acc2[4];
    #pragma unroll
    for (int jt = 0; jt < 4; ++jt) {
        const float bias = b2[jt * 16 + m];
        acc2[jt] = (f32x4){bias, bias, bias, bias};
        const _Float16* bw = w2t + (jt * 16 + m) * 64 + q * 8;
        half8 bf0 = *(const half8*)(bw);
        half8 bf1 = *(const half8*)(bw + 32);
        acc2[jt] = __builtin_amdgcn_mfma_f32_16x16x32_f16(c0, bf0, acc2[jt], 0, 0, 0);
        acc2[jt] = __builtin_amdgcn_mfma_f32_16x16x32_f16(c1, bf1, acc2[jt], 0, 0, 0);
    }
    asm volatile("s_waitcnt lgkmcnt(0)" ::: "memory");  // c0/c1 reads done before overwrite
    __builtin_amdgcn_sched_barrier(0);

    float psums[4], psqs[4];
    #pragma unroll
    for (int jt = 0; jt < 4; ++jt) {
        float ps = 0.f, pq = 0.f;
        #pragma unroll
        for (int r = 0; r < 4; ++r) {
            const int row = rbase + q * 4 + r;
            const float v = acc2[jt][r];
            const float vv = (nb + row < N_NODES) ? v : 0.f;
            ps += vv;
            pq += vv * vv;
            xts[row * 72 + jt * 16 + m] = (_Float16)v;
        }
        ps += __shfl_xor(ps, 16, 64); ps += __shfl_xor(ps, 32, 64);
        pq += __shfl_xor(pq, 16, 64); pq += __shfl_xor(pq, 32, 64);
        psums[jt] = ps; psqs[jt] = pq;
    }
    if (lane < 16) {
        #pragma unroll
        for (int jt = 0; jt < 4; ++jt) {
            bnred[w * 128 + jt * 16 + lane]      = psums[jt];
            bnred[w * 128 + 64 + jt * 16 + lane] = psqs[jt];
        }
    }
    asm volatile("s_waitcnt lgkmcnt(0)" ::: "memory");
    __builtin_amdgcn_sched_barrier(0);

    // coalesced fp16 h2 store (wave reads back only its own 16 rows)
    {
        const int rr = lane >> 2;
        const int cc = (lane & 3) * 16;
        const int gn = nb + rbase + rr;
        if (gn < N_NODES) {
            float4 r0 = *(const float4*)&xts[(rbase + rr) * 72 + cc];
            float4 r1 = *(const float4*)&xts[(rbase + rr) * 72 + cc + 8];
            *(float4*)(h216 + (size_t)gn * 64 + cc)     = r0;
            *(float4*)(h216 + (size_t)gn * 64 + cc + 8) = r1;
        }
    }

    // cross-wave BN fold -> one atomic per stat entry per block
    __syncthreads();
    if (t < 128) {
        const float v = bnred[t] + bnred[128 + t] + bnred[256 + t] + bnred[384 + t];
        unsafeAtomicAdd(stats + (size_t)(blockIdx.x & (NSHARD - 1)) * 128 + t, v);
    }
}

// ---------------------------------------------------------------------------
// finish16_k: folds the NSHARD stat shards into scale/shift per block
// (threads 0..127 each own one raw entry), then
// out = relu(h2*scale + shift) + feat. (verified r8)
// ---------------------------------------------------------------------------
__global__ __launch_bounds__(256) void finish16_k(
    const float* __restrict__ feat, const __half* __restrict__ h216,
    const float* __restrict__ stats, const float* __restrict__ gamma,
    const float* __restrict__ beta, float* __restrict__ out)
{
    __shared__ float raw[128];
    __shared__ float scs[64], shs[64];
    const int t = threadIdx.x;
    if (t < 128) {
        float s = 0.f;
        #pragma unroll
        for (int c = 0; c < NSHARD; ++c)
            s += stats[c * 128 + t];
        raw[t] = s;
    }
    __syncthreads();
    if (t < 64) {
        const float invN = 1.0f / (float)N_NODES;
        const float mean = raw[t] * invN;
        const float var  = raw[64 + t] * invN - mean * mean;
        const float scale = gamma[t] * rsqrtf(var + BN_EPS);
        scs[t] = scale;
        shs[t] = beta[t] - mean * scale;
    }
    __syncthreads();
    size_t i = (size_t)blockIdx.x * 256 + t;
    if (i < (size_t)N_NODES * D / 4) {
        int j = (int)((i * 4) & 63);
        const __half2* hp = (const __half2*)(h216 + i * 4);
        float2 h0 = __half22float2(hp[0]);
        float2 h1 = __half22float2(hp[1]);
        float4 f = *(const float4*)(feat + i * 4);
        float4 o;
        o.x = fmaxf(fmaf(h0.x, scs[j + 0], shs[j + 0]), 0.f) + f.x;
        o.y = fmaxf(fmaf(h0.y, scs[j + 1], shs[j + 1]), 0.f) + f.y;
        o.z = fmaxf(fmaf(h1.x, scs[j + 2], shs[j + 2]), 0.f) + f.z;
        o.w = fmaxf(fmaf(h1.y, scs[j + 3], shs[j + 3]), 0.f) + f.w;
        *(float4*)(out + i * 4) = o;
    }
}

// ===========================================================================
// fp32 fallback path (old CSR pipeline, int2 records), if workspace small.
// ===========================================================================
#define OCAP 7680

__global__ void bnstats_k(const float* __restrict__ stats,
                          const float* __restrict__ gamma,
                          const float* __restrict__ beta,
                          float* __restrict__ sf)
{
    int j = threadIdx.x;
    float s = 0.f, q = 0.f;
    for (int c = 0; c < NSHARD; ++c) {
        s += stats[c * 128 + j];
        q += stats[c * 128 + 64 + j];
    }
    const float invN = 1.0f / (float)N_NODES;
    float mean  = s * invN;
    float var   = q * invN - mean * mean;
    float scale = gamma[j] * rsqrtf(var + BN_EPS);
    sf[j]      = scale;
    sf[64 + j] = beta[j] - mean * scale;
}

__global__ __launch_bounds__(256) void bucket2_k(
    const int* __restrict__ src, const int* __restrict__ dst,
    int* __restrict__ bkt_cnt, int2* __restrict__ bktbuf)
{
    __shared__ int h[NBKT], base[NBKT], cur[NBKT];
    const int t = threadIdx.x;
    h[t] = 0; cur[t] = 0;
    __syncthreads();
    const int e0 = blockIdx.x * 4096;
    int s[16], d[16], b[16];
    #pragma unroll
    for (int i = 0; i < 16; ++i) {
        int e = e0 + i * 256 + t;
        if (e < N_EDGES) {
            s[i] = src[e];
            d[i] = dst[e];
            b[i] = d[i] / NPB;
            atomicAdd(&h[b[i]], 1);
        } else {
            b[i] = -1;
        }
    }
    __syncthreads();
    base[t] = atomicAdd(&bkt_cnt[t], h[t]);
    __syncthreads();
    #pragma unroll
    for (int i = 0; i < 16; ++i) {
        if (b[i] >= 0) {
            int p = atomicAdd(&cur[b[i]], 1);
            bktbuf[(size_t)b[i] * OCAP + base[b[i]] + p] = make_int2(s[i], d[i]);
        }
    }
}

__global__ __launch_bounds__(SORT_T) void sort2_k(
    const int2* __restrict__ bktbuf, const int* __restrict__ bkt_cnt,
    int* __restrict__ rowptr, int* __restrict__ col)
{
    __shared__ int h[NPB];
    __shared__ int cur[NPB];
    __shared__ int part[SORT_T];
    __shared__ int bsc[NBKT];

    const int b = blockIdx.x;
    const int t = threadIdx.x;
    const int nb0 = b * NPB;
    const int nodes_in = min(NPB, N_NODES - nb0);
    const int cnt = bkt_cnt[b];
    const int2* buf = bktbuf + (size_t)b * OCAP;

    if (t < NBKT) bsc[t] = bkt_cnt[t];
    __syncthreads();
    for (int off = 1; off < NBKT; off <<= 1) {
        int x = 0;
        if (t < NBKT) {
            x = bsc[t];
            if (t >= off) x += bsc[t - off];
        }
        __syncthreads();
        if (t < NBKT) bsc[t] = x;
        __syncthreads();
    }
    const int gbase = bsc[b] - cnt;

    if (t < NPB) h[t] = 0;
    __syncthreads();

    for (int i = t; i < cnt; i += SORT_T)
        atomicAdd(&h[buf[i].y - nb0], 1);
    __syncthreads();

    int a = (t < NPB) ? h[t] : 0;
    part[t] = a;
    __syncthreads();
    for (int off = 1; off < SORT_T; off <<= 1) {
        int x = part[t];
        int u = (t >= off) ? part[t - off] : 0;
        __syncthreads();
        part[t] = x + u;
        __syncthreads();
    }
    int excl = part[t] - a;
    if (t < NPB) {
        cur[t] = excl;
        if (t < nodes_in) rowptr[nb0 + t] = gbase + excl;
    }
    if (b == NBKT - 1 && t == 0) rowptr[N_NODES] = N_EDGES;
    __syncthreads();

    for (int i = t; i < cnt; i += SORT_T) {
        int2 r = buf[i];
        int slot = atomicAdd(&cur[r.y - nb0], 1);
        col[gbase + slot] = r.x;
    }
}

__global__ __launch_bounds__(256) void gather32_k(
    const float* __restrict__ feat, const int* __restrict__ rowptr,
    const int* __restrict__ col, const float* __restrict__ epsp,
    float* __restrict__ x)
{
    int node = blockIdx.x * 4 + (threadIdx.x >> 6);
    int lane = threadIdx.x & 63;
    if (node >= N_NODES) return;
    int g = lane >> 4;
    int c = (lane & 15) << 2;
    int lo = rowptr[node];
    int hi = rowptr[node + 1];
    float ax = 0.f, ay = 0.f, az = 0.f, aw = 0.f;
    int e = lo + g;
    for (; e + 4 < hi; e += 8) {
        int s0 = col[e];
        int s1 = col[e + 4];
        float4 v0 = *(const float4*)(feat + (size_t)s0 * D + c);
        float4 v1 = *(const float4*)(feat + (size_t)s1 * D + c);
        ax += v0.x; ay += v0.y; az += v0.z; aw += v0.w;
        ax += v1.x; ay += v1.y; az += v1.z; aw += v1.w;
    }
    if (e < hi) {
        float4 v = *(const float4*)(feat + (size_t)col[e] * D + c);
        ax += v.x; ay += v.y; az += v.z; aw += v.w;
    }
    #pragma unroll
    for (int off = 16; off <= 32; off <<= 1) {
        ax += __shfl_xor(ax, off, 64);
        ay += __shfl_xor(ay, off, 64);
        az += __shfl_xor(az, off, 64);
        aw += __shfl_xor(aw, off, 64);
    }
    if (g == 0) {
        float4 f = *(const float4*)(feat + (size_t)node * D + c);
        const float epsv = 1.0f + epsp[0];
        float4 r;
        r.x = fmaf(epsv, f.x, ax);
        r.y = fmaf(epsv, f.y, ay);
        r.z = fmaf(epsv, f.z, az);
        r.w = fmaf(epsv, f.w, aw);
        *(float4*)(x + (size_t)node * D + c) = r;
    }
}

__global__ __launch_bounds__(256) void mlp32_k(
    const float* __restrict__ x,
    const float* __restrict__ W1, const float* __restrict__ b1,
    const float* __restrict__ W2, const float* __restrict__ b2,
    float* __restrict__ h2out, float* __restrict__ stats)
{
    __shared__ float W1s[64 * 68];
    __shared__ float W2s[64 * 68];
    __shared__ float xs[64 * 65];
    __shared__ float b1s[64], b2s[64];

    const int t  = threadIdx.x;
    const int nb = blockIdx.x * 64;

    #pragma unroll
    for (int i = 0; i < 4; ++i) {
        int l  = t + i * 256;
        int k  = l >> 4;
        int j4 = (l & 15) << 2;
        *(float4*)(&W1s[k * 68 + j4]) = *(const float4*)(W1 + k * 64 + j4);
        *(float4*)(&W2s[k * 68 + j4]) = *(const float4*)(W2 + k * 64 + j4);
    }
    if (t < 64)       b1s[t]      = b1[t];
    else if (t < 128) b2s[t - 64] = b2[t - 64];

    #pragma unroll
    for (int i = 0; i < 2; ++i) {
        int n  = (t >> 3) + i * 32;
        int k8 = (t & 7) << 3;
        int gn = nb + n;
        float4 a = make_float4(0.f, 0.f, 0.f, 0.f), b = a;
        if (gn < N_NODES) {
            a = *(const float4*)(x + (size_t)gn * D + k8);
            b = *(const float4*)(x + (size_t)gn * D + k8 + 4);
        }
        *(float4*)&xs[n * 65 + k8]     = a;
        *(float4*)&xs[n * 65 + k8 + 4] = b;
    }
    __syncthreads();

    const int n0 = (t & 15) << 2;
    const int j0 = (t >> 4) << 2;
    const float* xr0 = &xs[(n0 + 0) * 65];
    const float* xr1 = &xs[(n0 + 1) * 65];
    const float* xr2 = &xs[(n0 + 2) * 65];
    const float* xr3 = &xs[(n0 + 3) * 65];

    float acc[4][4];
    #pragma unroll
    for (int a = 0; a < 4; ++a)
        #pragma unroll
        for (int b = 0; b < 4; ++b)
            acc[a][b] = b1s[j0 + b];

    #pragma unroll 8
    for (int k = 0; k < 64; ++k) {
        const float4 w = *(const float4*)(&W1s[k * 68 + j0]);
        const float x0 = xr0[k], x1 = xr1[k], x2 = xr2[k], x3 = xr3[k];
        acc[0][0] = fmaf(x0, w.x, acc[0][0]); acc[0][1] = fmaf(x0, w.y, acc[0][1]);
        acc[0][2] = fmaf(x0, w.z, acc[0][2]); acc[0][3] = fmaf(x0, w.w, acc[0][3]);
        acc[1][0] = fmaf(x1, w.x, acc[1][0]); acc[1][1] = fmaf(x1, w.y, acc[1][1]);
        acc[1][2] = fmaf(x1, w.z, acc[1][2]); acc[1][3] = fmaf(x1, w.w, acc[1][3]);
        acc[2][0] = fmaf(x2, w.x, acc[2][0]); acc[2][1] = fmaf(x2, w.y, acc[2][1]);
        acc[2][2] = fmaf(x2, w.z, acc[2][2]); acc[2][3] = fmaf(x2, w.w, acc[2][3]);
        acc[3][0] = fmaf(x3, w.x, acc[3][0]); acc[3][1] = fmaf(x3, w.y, acc[3][1]);
        acc[3][2] = fmaf(x3, w.z, acc[3][2]); acc[3][3] = fmaf(x3, w.w, acc[3][3]);
    }

    __syncthreads();
    #pragma unroll
    for (int a = 0; a < 4; ++a)
        #pragma unroll
        for (int b = 0; b < 4; ++b)
            xs[(n0 + a) * 65 + j0 + b] = fmaxf(acc[a][b], 0.0f);
    __syncthreads();

    float acc2[4][4];
    #pragma unroll
    for (int a = 0; a < 4; ++a)
        #pragma unroll
        for (int b = 0; b < 4; ++b)
            acc2[a][b] = b2s[j0 + b];

    #pragma unroll 8
    for (int k = 0; k < 64; ++k) {
        const float4 w = *(const float4*)(&W2s[k * 68 + j0]);
        const float x0 = xr0[k], x1 = xr1[k], x2 = xr2[k], x3 = xr3[k];
        acc2[0][0] = fmaf(x0, w.x, acc2[0][0]); acc2[0][1] = fmaf(x0, w.y, acc2[0][1]);
        acc2[0][2] = fmaf(x0, w.z, acc2[0][2]); acc2[0][3] = fmaf(x0, w.w, acc2[0][3]);
        acc2[1][0] = fmaf(x1, w.x, acc2[1][0]); acc2[1][1] = fmaf(x1, w.y, acc2[1][1]);
        acc2[1][2] = fmaf(x1, w.z, acc2[1][2]); acc2[1][3] = fmaf(x1, w.w, acc2[1][3]);
        acc2[2][0] = fmaf(x2, w.x, acc2[2][0]); acc2[2][1] = fmaf(x2, w.y, acc2[2][1]);
        acc2[2][2] = fmaf(x2, w.z, acc2[2][2]); acc2[2][3] = fmaf(x2, w.w, acc2[2][3]);
        acc2[3][0] = fmaf(x3, w.x, acc2[3][0]); acc2[3][1] = fmaf(x3, w.y, acc2[3][1]);
        acc2[3][2] = fmaf(x3, w.z, acc2[3][2]); acc2[3][3] = fmaf(x3, w.w, acc2[3][3]);
    }

    float psum[4] = {0.f, 0.f, 0.f, 0.f};
    float psq[4]  = {0.f, 0.f, 0.f, 0.f};
    #pragma unroll
    for (int a = 0; a < 4; ++a) {
        int gn = nb + n0 + a;
        if (gn < N_NODES) {
            float4 hh;
            hh.x = acc2[a][0]; hh.y = acc2[a][1]; hh.z = acc2[a][2]; hh.w = acc2[a][3];
            *(float4*)(h2out + (size_t)gn * 64 + j0) = hh;
            psum[0] += hh.x; psq[0] += hh.x * hh.x;
            psum[1] += hh.y; psq[1] += hh.y * hh.y;
            psum[2] += hh.z; psq[2] += hh.z * hh.z;
            psum[3] += hh.w; psq[3] += hh.w * hh.w;
        }
    }
    #pragma unroll
    for (int off = 8; off >= 1; off >>= 1)
        #pragma unroll
        for (int b = 0; b < 4; ++b) {
            psum[b] += __shfl_down(psum[b], off, 16);
            psq[b]  += __shfl_down(psq[b],  off, 16);
        }
    if ((t & 15) == 0) {
        float* sp = stats + (size_t)(blockIdx.x & (NSHARD - 1)) * 128;
        #pragma unroll
        for (int b = 0; b < 4; ++b) {
            unsafeAtomicAdd(sp + j0 + b,      psum[b]);
            unsafeAtomicAdd(sp + 64 + j0 + b, psq[b]);
        }
    }
}

__global__ __launch_bounds__(256) void finish_k(
    const float* __restrict__ feat, const float* __restrict__ sf,
    float* __restrict__ out)
{
    __shared__ float scs[64], shs[64];
    if (threadIdx.x < 64) {
        scs[threadIdx.x] = sf[threadIdx.x];
        shs[threadIdx.x] = sf[64 + threadIdx.x];
    }
    __syncthreads();
    size_t i = (size_t)blockIdx.x * 256 + threadIdx.x;
    if (i < (size_t)N_NODES * D / 4) {
        int j = (int)((i * 4) & 63);
        float4 h = *(float4*)(out + i * 4);
        float4 f = *(const float4*)(feat + i * 4);
        h.x = fmaxf(fmaf(h.x, scs[j + 0], shs[j + 0]), 0.f) + f.x;
        h.y = fmaxf(fmaf(h.y, scs[j + 1], shs[j + 1]), 0.f) + f.y;
        h.z = fmaxf(fmaf(h.z, scs[j + 2], shs[j + 2]), 0.f) + f.z;
        h.w = fmaxf(fmaf(h.w, scs[j + 3], shs[j + 3]), 0.f) + f.w;
        *(float4*)(out + i * 4) = h;
    }
}

extern "C" void kernel_launch(void* const* d_in, const int* in_sizes, int n_in,
                              void* d_out, int out_size, void* d_ws, size_t ws_size,
                              hipStream_t stream)
{
    const float* feat  = (const float*)d_in[0];
    const int*   src   = (const int*)d_in[1];
    const int*   dst   = (const int*)d_in[2];
    const float* eps   = (const float*)d_in[3];
    const float* W1    = (const float*)d_in[4];
    const float* b1    = (const float*)d_in[5];
    const float* W2    = (const float*)d_in[6];
    const float* b2    = (const float*)d_in[7];
    const float* gamma = (const float*)d_in[8];
    const float* beta  = (const float*)d_in[9];
    float* out = (float*)d_out;

    const size_t BKTSZ  = (size_t)NBKT * BKT_CAP * sizeof(int);    // 13.37 MB
    const size_t F16SZ  = (size_t)N_NODES * D * sizeof(__half);    // 12.8 MB
    const size_t COLSZ  = (size_t)N_EDGES * sizeof(int);           // 6.4 MB
    const size_t RPSZ   = ((size_t)(N_NODES + 1) * sizeof(int) + 15) & ~(size_t)15;
    const size_t STATSZ = (size_t)NSHARD * 128 * sizeof(float);    // 16 KB
    const size_t CNTSZ  = (size_t)NBKT * sizeof(int);              // 1 KB
    const size_t TAIL   = STATSZ + CNTSZ + 128 * 4 + 2 * 4096 * sizeof(_Float16) + 256;
    const size_t need   = BKTSZ + F16SZ + COLSZ + RPSZ + TAIL;     // ~33.2 MB

    if (ws_size >= need) {
        // fp16 path (r8-verified layout). Aliases: x16 over bktbuf (dead
        // after sortp_k; BKT_CAP oversized to cover x16 + mfma tail
        // overread), h216 over feat16 (dead after gatherq_k).
        char* p = (char*)d_ws;
        int*    bktbuf  = (int*)p;
        __half* x16     = (__half*)p;
        __half* feat16  = (__half*)(p + BKTSZ);
        __half* h216    = feat16;
        int*    col     = (int*)(p + BKTSZ + F16SZ);
        int*    rowptr  = (int*)(p + BKTSZ + F16SZ + COLSZ);
        float*  stats   = (float*)(p + BKTSZ + F16SZ + COLSZ + RPSZ);
        int*    bkt_cnt = (int*)(stats + NSHARD * 128);
        float*  sf      = (float*)(bkt_cnt + NBKT);
        _Float16* w1t   = (_Float16*)(sf + 128);
        _Float16* w2t   = w1t + 4096;
        (void)sf;

        // zero bkt_cnt only (stats zeroed by sortp block 0)
        hipMemsetAsync(bkt_cnt, 0, CNTSZ, stream);
        prep_k<<<NBBLK + 3125 + 1, 256, 0, stream>>>(src, dst, bkt_cnt, bktbuf,
                                                     feat, feat16, W1, W2, w1t, w2t);
        sortp_k<<<NBKT, SORT_T, 0, stream>>>(bktbuf, bkt_cnt, rowptr, col, stats);
        gatherq_k<<<(N_NODES + 63) / 64, 256, 0, stream>>>(feat16, rowptr, col, eps, x16);
        mfma_mlp2_k<<<(N_NODES + 63) / 64, 256, 0, stream>>>(x16, w1t, w2t, b1, b2, h216, stats);
        finish16_k<<<(N_NODES * D / 4 + 255) / 256, 256, 0, stream>>>(
            feat, h216, stats, gamma, beta, out);
    } else {
        // fp32 fallback (old CSR pipeline, int2 records). x32 aliases bktbuf.
        const size_t X32SZ = (size_t)N_NODES * D * sizeof(float);
        char* p = (char*)d_ws;
        float* x32    = (float*)p;
        int2*  bktbuf = (int2*)p;
        int*   col    = (int*)(p + X32SZ);
        int*   rowptr = col + N_EDGES;
        float* stats  = (float*)(rowptr + N_NODES + 1);
        int*   bkt_cnt = (int*)(stats + NSHARD * 128);
        float* sf     = (float*)(bkt_cnt + NBKT);

        hipMemsetAsync(stats, 0, STATSZ + NBKT * 4, stream);
        bucket2_k<<<(N_EDGES + 4095) / 4096, 256, 0, stream>>>(src, dst, bkt_cnt, bktbuf);
        sort2_k<<<NBKT, SORT_T, 0, stream>>>(bktbuf, bkt_cnt, rowptr, col);
        gather32_k<<<(N_NODES + 3) / 4, 256, 0, stream>>>(feat, rowptr, col, eps, x32);
        mlp32_k<<<(N_NODES + 63) / 64, 256, 0, stream>>>(x32, W1, b1, W2, b2, out, stats);
        bnstats_k<<<1, 64, 0, stream>>>(stats, gamma, beta, sf);
        finish_k<<<(N_NODES * D / 4 + 255) / 256, 256, 0, stream>>>(feat, sf, out);
    }
}